// Round 14
// baseline (180.334 us; speedup 1.0000x reference)
//
#include <hip/hip_runtime.h>

#define BATCH 64
#define HH 512
#define WW 512
#define TH 64                  // output rows per strip (r14: was 32; halo 74/64=1.16x)
#define KS 11
#define PADK 5
#define NIN (TH + 2 * PADK)    // 74 valid input rows per strip (76 slots, 2 cut)
#define NF4 262                // float4 slots/row: 3 pad + 256 px-pairs + 3 pad
#define NPIX (64.0 * 512.0 * 512.0)

// r13 ({s,d}-basis scalar, bench-best 170.4 us) with total work cut:
// TH=64 strips (halo overhead 1.31x -> 1.16x: -12% h-conv/staging/LDS/HBM;
// grid 512 blocks = exactly 2 work = 2 resident blocks/CU) and the
// wave-uniform zero-tap skip (even-parity waves have wx0==0, odd have
// wz5==0 -> SGPR-branch around the dead 6-inst side; parity is per-wave).
// NOTE (r13 lesson): optimize BENCH dur_us. rocprof single-dispatch time
// is cold-L3 + counter-replay and mis-ranks kernels; the bench regime is
// warm (128 MB inputs are L3-resident across graph iterations) where this
// kernel is VALU-throughput-bound.
// Carried, each HW-proven: {s,d}={a+b,a-b} staging (r12/r13 algebra), 6
// aligned b128 reads/row (8 B/px), wave-parity mapping with SGPR weights
// (r10), 44-named-scalar ring (r3/r7), 4-row dbuf chunks + ONE barrier
// per chunk (r6), launch_bounds (512,2) ONLY (r4/r9), PACKED FP32 CLOSED
// (r12: VGPR pairs cross the 64-reg occupancy step).
__global__ void __launch_bounds__(512, 2) ssim_main_kernel(
    const float* __restrict__ img1, const float* __restrict__ img2,
    double* __restrict__ accum) {
  constexpr float GA[KS] = {
      0.00102838f, 0.00759884f, 0.03600087f, 0.10936069f, 0.21300553f,
      0.26601172f, 0.21300553f, 0.10936069f, 0.03600087f, 0.00759884f,
      0.00102838f};
  const float C1v = 1e-4f, C2v = 9e-4f;

  const int t  = threadIdx.x;          // 0..511
  const int r0 = blockIdx.x * TH;      // first output row of strip
  const int b  = blockIdx.y;           // batch index

  const float2* __restrict__ pp1 =
      reinterpret_cast<const float2*>(img1 + (size_t)b * HH * WW);
  const float2* __restrict__ pp2 =
      reinterpret_cast<const float2*>(img2 + (size_t)b * HH * WW);

  // Slot s holds px pair (2(s-3), 2(s-3)+1) as {s0,d0,s1,d1}.
  __shared__ float4 s4[2][4][NF4];
  __shared__ float wsum[8];

  // Zero horizontal pads of both buffers once (slots 0..2 and 259..261).
  if (t < 6) {
    const int idx = (t < 3) ? t : (256 + t);
#pragma unroll
    for (int bi = 0; bi < 2; ++bi)
#pragma unroll
      for (int r = 0; r < 4; ++r) s4[bi][r][idx] = make_float4(0.f, 0.f, 0.f, 0.f);
  }

  const int pi = t & 255;              // pair index (stage + window base)
  const int jA = (t >> 8) & 1;         // staged rows jA, jA+2; col parity
  const int jB = jA + 2;
  const int base = pi + jA;            // first b128 slot of the 12-px window

  // Wave-uniform parity -> SGPR weights (readfirstlane-forced, r10-proven
  // clean codegen). wx0 dead for even waves, wz5 dead for odd (skipped).
#define RFL(x) __int_as_float(__builtin_amdgcn_readfirstlane(__float_as_int(x)))
  const bool oddp = ((__builtin_amdgcn_readfirstlane(t) >> 8) & 1) != 0;
  const float wx0 = RFL(GA[0]);                 // used only when oddp
  const float wx1 = RFL(oddp ? GA[2]  : GA[1]);
  const float wx2 = RFL(oddp ? GA[4]  : GA[3]);
  const float wx3 = RFL(oddp ? GA[6]  : GA[5]);
  const float wx4 = RFL(oddp ? GA[8]  : GA[7]);
  const float wx5 = RFL(oddp ? GA[10] : GA[9]);
  const float wz0 = RFL(oddp ? GA[1]  : GA[0]);
  const float wz1 = RFL(oddp ? GA[3]  : GA[2]);
  const float wz2 = RFL(oddp ? GA[5]  : GA[4]);
  const float wz3 = RFL(oddp ? GA[7]  : GA[6]);
  const float wz4 = RFL(oddp ? GA[9]  : GA[8]);
  const float wz5 = RFL(GA[10]);                // used only when !oddp

  // Ring: 44 named scalars; slot s holds h-conv of input row rc (rc%11==s):
  // zS = conv(s), zD = conv(d), zU = conv(s^2), zV = conv(d^2).
#define DECLR(s) float zS##s = 0.f, zD##s = 0.f, zU##s = 0.f, zV##s = 0.f;
  DECLR(0) DECLR(1) DECLR(2) DECLR(3) DECLR(4) DECLR(5)
  DECLR(6) DECLR(7) DECLR(8) DECLR(9) DECLR(10)

  float2 taA, tbA, taB, tbB;           // staging regs (2 rows/thread)
  float local = 0.f;

  // Load the two staged rows of chunk k_ (rows jA and jB=jA+2). jA row is
  // always rc<=73<NIN; jB row of chunk 18 is cut.
#define LOADC(k_) {                                                     \
    taA = make_float2(0.f, 0.f); tbA = make_float2(0.f, 0.f);           \
    taB = make_float2(0.f, 0.f); tbB = make_float2(0.f, 0.f);           \
    { const int rr_ = r0 - PADK + 4 * (k_) + jA;                        \
      if ((unsigned)rr_ < HH) { const int o_ = rr_ * (WW / 2) + pi;     \
        taA = pp1[o_]; tbA = pp2[o_]; } }                               \
    if (4 * (k_) + jB < NIN) {                                          \
      const int rr_ = r0 - PADK + 4 * (k_) + jB;                        \
      if ((unsigned)rr_ < HH) { const int o_ = rr_ * (WW / 2) + pi;     \
        taB = pp1[o_]; tbB = pp2[o_]; } } }

  // Stage chunk k_ into buffer k_&1: {s,d} basis, one b128 per staged row.
#define WRITEC(k_) {                                                    \
    s4[(k_) & 1][jA][pi + 3] = make_float4(                             \
        taA.x + tbA.x, taA.x - tbA.x, taA.y + tbA.y, taA.y - tbA.y);    \
    if (4 * (k_) + jB < NIN)                                            \
      s4[(k_) & 1][jB][pi + 3] = make_float4(                           \
          taB.x + tbB.x, taB.x - tbB.x, taB.y + tbB.y, taB.y - tbB.y); }

  // One px side: 2 mul + 4 fma into the 4 accumulators.
#define HX(vx_, vy_, w_) {                                              \
    hS = fmaf(w_, vx_, hS);          hD = fmaf(w_, vy_, hD);            \
    hU = fmaf(w_, vx_ * vx_, hU);    hV = fmaf(w_, vy_ * vy_, hV); }

  // Generic b128 of the window: 2 px {s,d}.
#define HK(bb_, j_, kk_, wx_, wz_) {                                    \
    const float4 v = s4[bb_][j_][base + kk_];                           \
    HX(v.x, v.y, wx_) HX(v.z, v.w, wz_) }

  // kk=0: x-side weight is 0 for even waves -> SGPR-branch skip.
#define HK0(bb_, j_) {                                                  \
    const float4 v = s4[bb_][j_][base + 0];                             \
    if (oddp) { HX(v.x, v.y, wx0) }                                     \
    HX(v.z, v.w, wz0) }

  // kk=5: z-side weight is 0 for odd waves -> SGPR-branch skip.
#define HK5(bb_, j_) {                                                  \
    const float4 v = s4[bb_][j_][base + 5];                             \
    HX(v.x, v.y, wx5)                                                   \
    if (!oddp) { HX(v.z, v.w, wz5) } }

  // Horizontal conv of LDS row j_ of buffer bb_ -> ring slot S. 6 b128.
#define HBODY(bb_, j_, S) {                                             \
    float hS = 0.f, hD = 0.f, hU = 0.f, hV = 0.f;                       \
    HK0(bb_, j_)             HK(bb_, j_, 1, wx1, wz1)                   \
    HK(bb_, j_, 2, wx2, wz2) HK(bb_, j_, 3, wx3, wz3)                   \
    HK(bb_, j_, 4, wx4, wz4) HK5(bb_, j_)                               \
    zS##S = hS; zD##S = hD; zU##S = hU; zV##S = hV; }

  // Vertical conv: explicit rotation, slot names literal.
#define VC(P, s0,s1,s2v,s3,s4v,s5,s6v,s7,s8,s9,s10)                     \
  fmaf(GA[10], P##s10, fmaf(GA[9], P##s9, fmaf(GA[8], P##s8,            \
  fmaf(GA[7], P##s7, fmaf(GA[6], P##s6v, fmaf(GA[5], P##s5,             \
  fmaf(GA[4], P##s4v, fmaf(GA[3], P##s3, fmaf(GA[2], P##s2v,            \
  fmaf(GA[1], P##s1, GA[0] * P##s0))))))))))

  // Reconstruct (r12/r13-validated algebra): Pq=mS^2-mD^2, Qq=mS^2+mD^2.
#define VOUTBODY(s0,s1,s2v,s3,s4v,s5,s6v,s7,s8,s9,s10)                  \
  {                                                                     \
    const float mS = VC(zS, s0,s1,s2v,s3,s4v,s5,s6v,s7,s8,s9,s10);      \
    const float mD = VC(zD, s0,s1,s2v,s3,s4v,s5,s6v,s7,s8,s9,s10);      \
    const float mU = VC(zU, s0,s1,s2v,s3,s4v,s5,s6v,s7,s8,s9,s10);      \
    const float mV = VC(zV, s0,s1,s2v,s3,s4v,s5,s6v,s7,s8,s9,s10);      \
    const float uu = mS * mS, vv = mD * mD;                             \
    const float Pq = uu - vv, Qq = uu + vv;                             \
    const float num = fmaf(0.5f, Pq, C1v) *                             \
                      fmaf(0.5f, (mU - mV) - Pq, C2v);                  \
    const float den = fmaf(0.5f, Qq, C1v) *                             \
                      fmaf(0.5f, (mU + mV) - Qq, C2v);                  \
    local = fmaf(num, __builtin_amdgcn_rcpf(den), local);               \
  }

#define ROT0  0,1,2,3,4,5,6,7,8,9,10
#define ROT1  1,2,3,4,5,6,7,8,9,10,0
#define ROT2  2,3,4,5,6,7,8,9,10,0,1
#define ROT3  3,4,5,6,7,8,9,10,0,1,2
#define ROT4  4,5,6,7,8,9,10,0,1,2,3
#define ROT5  5,6,7,8,9,10,0,1,2,3,4
#define ROT6  6,7,8,9,10,0,1,2,3,4,5
#define ROT7  7,8,9,10,0,1,2,3,4,5,6
#define ROT8  8,9,10,0,1,2,3,4,5,6,7
#define ROT9  9,10,0,1,2,3,4,5,6,7,8
#define ROT10 10,0,1,2,3,4,5,6,7,8,9
#define VOUTE(...) VOUTBODY(__VA_ARGS__)

#define ROWH(bb_, j_, S)      { HBODY(bb_, j_, S) }
#define ROWO(bb_, j_, S, R_)  { HBODY(bb_, j_, S) VOUTE(R_) }

  // Prologue: prefetch chunk 0.
  LOADC(0)

  // Per chunk ii (buf = ii&1): write staged regs; ONE barrier; prefetch
  // chunk ii+1; compute the 4 rows. rc = 4*ii+j; ring slot S = rc%11;
  // output row rc-10 emitted when rc >= 10, rotation start (rc+1)%11.
  // 19 chunks (rc 0..73; rc 74,75 cut).
  // ii=0: rc 0-3
  WRITEC(0) __syncthreads(); LOADC(1)
  ROWH(0,0,0) ROWH(0,1,1) ROWH(0,2,2) ROWH(0,3,3)
  // ii=1: rc 4-7
  WRITEC(1) __syncthreads(); LOADC(2)
  ROWH(1,0,4) ROWH(1,1,5) ROWH(1,2,6) ROWH(1,3,7)
  // ii=2: rc 8-11 (rc10,11 -> out rows 0,1)
  WRITEC(2) __syncthreads(); LOADC(3)
  ROWH(0,0,8) ROWH(0,1,9)
  ROWO(0,2,10, ROT0) ROWO(0,3,0, ROT1)
  // ii=3: rc 12-15
  WRITEC(3) __syncthreads(); LOADC(4)
  ROWO(1,0,1, ROT2) ROWO(1,1,2, ROT3) ROWO(1,2,3, ROT4) ROWO(1,3,4, ROT5)
  // ii=4: rc 16-19
  WRITEC(4) __syncthreads(); LOADC(5)
  ROWO(0,0,5, ROT6) ROWO(0,1,6, ROT7) ROWO(0,2,7, ROT8) ROWO(0,3,8, ROT9)
  // ii=5: rc 20-23
  WRITEC(5) __syncthreads(); LOADC(6)
  ROWO(1,0,9, ROT10) ROWO(1,1,10, ROT0) ROWO(1,2,0, ROT1) ROWO(1,3,1, ROT2)
  // ii=6: rc 24-27
  WRITEC(6) __syncthreads(); LOADC(7)
  ROWO(0,0,2, ROT3) ROWO(0,1,3, ROT4) ROWO(0,2,4, ROT5) ROWO(0,3,5, ROT6)
  // ii=7: rc 28-31
  WRITEC(7) __syncthreads(); LOADC(8)
  ROWO(1,0,6, ROT7) ROWO(1,1,7, ROT8) ROWO(1,2,8, ROT9) ROWO(1,3,9, ROT10)
  // ii=8: rc 32-35
  WRITEC(8) __syncthreads(); LOADC(9)
  ROWO(0,0,10, ROT0) ROWO(0,1,0, ROT1) ROWO(0,2,1, ROT2) ROWO(0,3,2, ROT3)
  // ii=9: rc 36-39
  WRITEC(9) __syncthreads(); LOADC(10)
  ROWO(1,0,3, ROT4) ROWO(1,1,4, ROT5) ROWO(1,2,5, ROT6) ROWO(1,3,6, ROT7)
  // ii=10: rc 40-43
  WRITEC(10) __syncthreads(); LOADC(11)
  ROWO(0,0,7, ROT8) ROWO(0,1,8, ROT9) ROWO(0,2,9, ROT10) ROWO(0,3,10, ROT0)
  // ii=11: rc 44-47
  WRITEC(11) __syncthreads(); LOADC(12)
  ROWO(1,0,0, ROT1) ROWO(1,1,1, ROT2) ROWO(1,2,2, ROT3) ROWO(1,3,3, ROT4)
  // ii=12: rc 48-51
  WRITEC(12) __syncthreads(); LOADC(13)
  ROWO(0,0,4, ROT5) ROWO(0,1,5, ROT6) ROWO(0,2,6, ROT7) ROWO(0,3,7, ROT8)
  // ii=13: rc 52-55
  WRITEC(13) __syncthreads(); LOADC(14)
  ROWO(1,0,8, ROT9) ROWO(1,1,9, ROT10) ROWO(1,2,10, ROT0) ROWO(1,3,0, ROT1)
  // ii=14: rc 56-59
  WRITEC(14) __syncthreads(); LOADC(15)
  ROWO(0,0,1, ROT2) ROWO(0,1,2, ROT3) ROWO(0,2,3, ROT4) ROWO(0,3,4, ROT5)
  // ii=15: rc 60-63
  WRITEC(15) __syncthreads(); LOADC(16)
  ROWO(1,0,5, ROT6) ROWO(1,1,6, ROT7) ROWO(1,2,7, ROT8) ROWO(1,3,8, ROT9)
  // ii=16: rc 64-67
  WRITEC(16) __syncthreads(); LOADC(17)
  ROWO(0,0,9, ROT10) ROWO(0,1,10, ROT0) ROWO(0,2,0, ROT1) ROWO(0,3,1, ROT2)
  // ii=17: rc 68-71
  WRITEC(17) __syncthreads(); LOADC(18)
  ROWO(1,0,2, ROT3) ROWO(1,1,3, ROT4) ROWO(1,2,4, ROT5) ROWO(1,3,5, ROT6)
  // ii=18: rc 72,73 (out rows 62,63; rc 74,75 cut)
  WRITEC(18) __syncthreads();
  ROWO(0,0,6, ROT7) ROWO(0,1,7, ROT8)

  // Block reduction: wave64 shuffle -> LDS -> one double atomic per block.
#pragma unroll
  for (int off = 32; off > 0; off >>= 1) local += __shfl_down(local, off, 64);
  const int wave = t >> 6;
  const int lane = t & 63;
  if (lane == 0) wsum[wave] = local;
  __syncthreads();
  if (t == 0) {
    float s = 0.f;
#pragma unroll
    for (int w = 0; w < 8; ++w) s += wsum[w];
    atomicAdd(accum, (double)s);
  }
}

__global__ void ssim_final_kernel(const double* __restrict__ accum,
                                  float* __restrict__ out) {
  out[0] = 1.0f - (float)(accum[0] / NPIX);
}

extern "C" void kernel_launch(void* const* d_in, const int* in_sizes, int n_in,
                              void* d_out, int out_size, void* d_ws, size_t ws_size,
                              hipStream_t stream) {
  const float* img1 = (const float*)d_in[0];
  const float* img2 = (const float*)d_in[1];
  double* accum = (double*)d_ws;
  hipMemsetAsync(accum, 0, sizeof(double), stream);

  dim3 grid(HH / TH, BATCH);
  ssim_main_kernel<<<grid, 512, 0, stream>>>(img1, img2, accum);
  ssim_final_kernel<<<1, 1, 0, stream>>>(accum, (float*)d_out);
}

// Round 15
// 169.653 us; speedup vs baseline: 1.0630x; 1.0630x over previous
//
#include <hip/hip_runtime.h>

#define BATCH 64
#define HH 512
#define WW 512
#define TH 32                  // output rows per strip
#define KS 11
#define PADK 5
#define NIN (TH + 2 * PADK)    // 42 valid input rows per strip (44 slots, 2 cut)
#define NF4 262                // float4 slots/row: 3 pad + 256 px-pairs + 3 pad
#define NPIX (64.0 * 512.0 * 512.0)

// SESSION CHAMPION (r13: bench 170.4 us — best of 15 rounds), resubmitted
// after r14's TH=64 + zero-tap-skip experiment regressed (180.3; VGPR
// 48->120 from branch-split live ranges, waves/CU 32->16).
// Design: 512 threads, 1 col/thread, TH=32 strips -> grid 1024 = 4
// blocks/CU, ALL resident (LDS 33.8 KB x4 = 135 KB, VGPR 48 <= 64-step)
// = the 32-wave/CU hardware occupancy maximum. Stage {s,d}={a+b,a-b}
// per px (8 B) in pair-packed float4 {s0,d0,s1,d1}; h-conv reads the
// 12-px window as 6 aligned ds_read_b128; per-px cost 6 VALU inst
// (2 mul + 4 fma). Wave-parity mapping (waves 0-3 even cols, 4-7 odd)
// makes tap alignment wave-uniform -> weights in SGPRs via readfirstlane.
// Reconstruction: mu1mu2=(mS^2-mD^2)/4, mu1^2+mu2^2=(mS^2+mD^2)/2,
// E[ab]=(mU-mV)/4, E[a^2+b^2]=(mU+mV)/2.
// CLOSED PATHS (each with measured counter evidence): tight launch_bounds
// caps (r4/r9: wholesale spill), packed fp32 (r12: VGPR pairs cross the
// 64-reg occupancy step -> stall-bound), barrier removal (r6: barriers
// double as live-range fences), TH=64 (r14: halves resident waves),
// per-lane parity weights (r8: remat storm), branchy zero-tap skip
// (r14: live-range split). Ring MUST be named scalars (r0/r2: SROA runs
// before unrolling -> array rings land in scratch).
__global__ void __launch_bounds__(512, 2) ssim_main_kernel(
    const float* __restrict__ img1, const float* __restrict__ img2,
    double* __restrict__ accum) {
  constexpr float GA[KS] = {
      0.00102838f, 0.00759884f, 0.03600087f, 0.10936069f, 0.21300553f,
      0.26601172f, 0.21300553f, 0.10936069f, 0.03600087f, 0.00759884f,
      0.00102838f};
  const float C1v = 1e-4f, C2v = 9e-4f;

  const int t  = threadIdx.x;          // 0..511
  const int r0 = blockIdx.x * TH;      // first output row of strip
  const int b  = blockIdx.y;           // batch index

  const float2* __restrict__ pp1 =
      reinterpret_cast<const float2*>(img1 + (size_t)b * HH * WW);
  const float2* __restrict__ pp2 =
      reinterpret_cast<const float2*>(img2 + (size_t)b * HH * WW);

  // Slot s holds px pair (2(s-3), 2(s-3)+1) as {s0,d0,s1,d1}.
  __shared__ float4 s4[2][4][NF4];
  __shared__ float wsum[8];

  // Zero horizontal pads of both buffers once (slots 0..2 and 259..261).
  if (t < 6) {
    const int idx = (t < 3) ? t : (256 + t);
#pragma unroll
    for (int bi = 0; bi < 2; ++bi)
#pragma unroll
      for (int r = 0; r < 4; ++r) s4[bi][r][idx] = make_float4(0.f, 0.f, 0.f, 0.f);
  }

  const int pi = t & 255;              // pair index (stage + window base)
  const int jA = (t >> 8) & 1;         // staged rows jA, jA+2; col parity
  const int jB = jA + 2;
  const int base = pi + jA;            // first b128 slot of the 12-px window

  // Wave-uniform parity -> SGPR weights (readfirstlane-forced; measured
  // clean at VGPR 48 / zero scratch in r10/r13).
#define RFL(x) __int_as_float(__builtin_amdgcn_readfirstlane(__float_as_int(x)))
  const bool oddp = ((__builtin_amdgcn_readfirstlane(t) >> 8) & 1) != 0;
  const float wx0 = RFL(oddp ? GA[0]  : 0.f);
  const float wx1 = RFL(oddp ? GA[2]  : GA[1]);
  const float wx2 = RFL(oddp ? GA[4]  : GA[3]);
  const float wx3 = RFL(oddp ? GA[6]  : GA[5]);
  const float wx4 = RFL(oddp ? GA[8]  : GA[7]);
  const float wx5 = RFL(oddp ? GA[10] : GA[9]);
  const float wz0 = RFL(oddp ? GA[1]  : GA[0]);
  const float wz1 = RFL(oddp ? GA[3]  : GA[2]);
  const float wz2 = RFL(oddp ? GA[5]  : GA[4]);
  const float wz3 = RFL(oddp ? GA[7]  : GA[6]);
  const float wz4 = RFL(oddp ? GA[9]  : GA[8]);
  const float wz5 = RFL(oddp ? 0.f    : GA[10]);

  // Ring: 44 named scalars; slot s holds h-conv of input row rc (rc%11==s):
  // zS = conv(s), zD = conv(d), zU = conv(s^2), zV = conv(d^2).
#define DECLR(s) float zS##s = 0.f, zD##s = 0.f, zU##s = 0.f, zV##s = 0.f;
  DECLR(0) DECLR(1) DECLR(2) DECLR(3) DECLR(4) DECLR(5)
  DECLR(6) DECLR(7) DECLR(8) DECLR(9) DECLR(10)

  float2 taA, tbA, taB, tbB;           // staging regs (2 rows/thread)
  float local = 0.f;

  // Load the two staged rows of chunk k_ (rows jA and jB=jA+2). jA row is
  // always rc<=41<NIN; jB row of chunk 10 is cut.
#define LOADC(k_) {                                                     \
    taA = make_float2(0.f, 0.f); tbA = make_float2(0.f, 0.f);           \
    taB = make_float2(0.f, 0.f); tbB = make_float2(0.f, 0.f);           \
    { const int rr_ = r0 - PADK + 4 * (k_) + jA;                        \
      if ((unsigned)rr_ < HH) { const int o_ = rr_ * (WW / 2) + pi;     \
        taA = pp1[o_]; tbA = pp2[o_]; } }                               \
    if (4 * (k_) + jB < NIN) {                                          \
      const int rr_ = r0 - PADK + 4 * (k_) + jB;                        \
      if ((unsigned)rr_ < HH) { const int o_ = rr_ * (WW / 2) + pi;     \
        taB = pp1[o_]; tbB = pp2[o_]; } } }

  // Stage chunk k_ into buffer k_&1: {s,d} basis, one b128 per staged
  // row: {s0,d0,s1,d1}. (Border px have a=b=0 -> s=d=0, consistent with
  // the zero pads.)
#define WRITEC(k_) {                                                    \
    s4[(k_) & 1][jA][pi + 3] = make_float4(                             \
        taA.x + tbA.x, taA.x - tbA.x, taA.y + tbA.y, taA.y - tbA.y);    \
    if (4 * (k_) + jB < NIN)                                            \
      s4[(k_) & 1][jB][pi + 3] = make_float4(                           \
          taB.x + tbB.x, taB.x - tbB.x, taB.y + tbB.y, taB.y - tbB.y); }

  // One b128 of the window: 2 px {s,d}; per px 2 mul + 4 fma.
#define HK(bb_, j_, kk_, wx_, wz_) {                                    \
    const float4 v = s4[bb_][j_][base + kk_];                           \
    hS = fmaf(wx_, v.x, hS);          hD = fmaf(wx_, v.y, hD);          \
    hU = fmaf(wx_, v.x * v.x, hU);    hV = fmaf(wx_, v.y * v.y, hV);    \
    hS = fmaf(wz_, v.z, hS);          hD = fmaf(wz_, v.w, hD);          \
    hU = fmaf(wz_, v.z * v.z, hU);    hV = fmaf(wz_, v.w * v.w, hV); }

  // Horizontal conv of LDS row j_ of buffer bb_ -> ring slot S. 6 b128.
#define HBODY(bb_, j_, S) {                                             \
    float hS = 0.f, hD = 0.f, hU = 0.f, hV = 0.f;                       \
    HK(bb_, j_, 0, wx0, wz0) HK(bb_, j_, 1, wx1, wz1)                   \
    HK(bb_, j_, 2, wx2, wz2) HK(bb_, j_, 3, wx3, wz3)                   \
    HK(bb_, j_, 4, wx4, wz4) HK(bb_, j_, 5, wx5, wz5)                   \
    zS##S = hS; zD##S = hD; zU##S = hU; zV##S = hV; }

  // Vertical conv: explicit rotation, slot names literal.
#define VC(P, s0,s1,s2v,s3,s4v,s5,s6v,s7,s8,s9,s10)                     \
  fmaf(GA[10], P##s10, fmaf(GA[9], P##s9, fmaf(GA[8], P##s8,            \
  fmaf(GA[7], P##s7, fmaf(GA[6], P##s6v, fmaf(GA[5], P##s5,             \
  fmaf(GA[4], P##s4v, fmaf(GA[3], P##s3, fmaf(GA[2], P##s2v,            \
  fmaf(GA[1], P##s1, GA[0] * P##s0))))))))))

  // Reconstruct: with Pq=mS^2-mD^2, Qq=mS^2+mD^2:
  //   num = (0.5*Pq + C1) * (0.5*((mU-mV) - Pq) + C2)
  //   den = (0.5*Qq + C1) * (0.5*((mU+mV) - Qq) + C2)
#define VOUTBODY(s0,s1,s2v,s3,s4v,s5,s6v,s7,s8,s9,s10)                  \
  {                                                                     \
    const float mS = VC(zS, s0,s1,s2v,s3,s4v,s5,s6v,s7,s8,s9,s10);      \
    const float mD = VC(zD, s0,s1,s2v,s3,s4v,s5,s6v,s7,s8,s9,s10);      \
    const float mU = VC(zU, s0,s1,s2v,s3,s4v,s5,s6v,s7,s8,s9,s10);      \
    const float mV = VC(zV, s0,s1,s2v,s3,s4v,s5,s6v,s7,s8,s9,s10);      \
    const float uu = mS * mS, vv = mD * mD;                             \
    const float Pq = uu - vv, Qq = uu + vv;                             \
    const float num = fmaf(0.5f, Pq, C1v) *                             \
                      fmaf(0.5f, (mU - mV) - Pq, C2v);                  \
    const float den = fmaf(0.5f, Qq, C1v) *                             \
                      fmaf(0.5f, (mU + mV) - Qq, C2v);                  \
    local = fmaf(num, __builtin_amdgcn_rcpf(den), local);               \
  }

#define ROT0  0,1,2,3,4,5,6,7,8,9,10
#define ROT1  1,2,3,4,5,6,7,8,9,10,0
#define ROT2  2,3,4,5,6,7,8,9,10,0,1
#define ROT3  3,4,5,6,7,8,9,10,0,1,2
#define ROT4  4,5,6,7,8,9,10,0,1,2,3
#define ROT5  5,6,7,8,9,10,0,1,2,3,4
#define ROT6  6,7,8,9,10,0,1,2,3,4,5
#define ROT7  7,8,9,10,0,1,2,3,4,5,6
#define ROT8  8,9,10,0,1,2,3,4,5,6,7
#define ROT9  9,10,0,1,2,3,4,5,6,7,8
#define ROT10 10,0,1,2,3,4,5,6,7,8,9
#define VOUTE(...) VOUTBODY(__VA_ARGS__)

#define ROWH(bb_, j_, S)      { HBODY(bb_, j_, S) }
#define ROWO(bb_, j_, S, R_)  { HBODY(bb_, j_, S) VOUTE(R_) }

  // Prologue: prefetch chunk 0.
  LOADC(0)

  // Per chunk ii (buf = ii&1): write staged regs; ONE barrier; prefetch
  // chunk ii+1; compute the 4 rows. rc = 4*ii+j; ring slot S = rc%11;
  // output row rc-10 emitted when rc >= 10, rotation start (rc+1)%11.
  // ii=0: rc 0-3
  WRITEC(0) __syncthreads(); LOADC(1)
  ROWH(0,0,0) ROWH(0,1,1) ROWH(0,2,2) ROWH(0,3,3)
  // ii=1: rc 4-7
  WRITEC(1) __syncthreads(); LOADC(2)
  ROWH(1,0,4) ROWH(1,1,5) ROWH(1,2,6) ROWH(1,3,7)
  // ii=2: rc 8-11 (rc10,11 -> output rows 0,1)
  WRITEC(2) __syncthreads(); LOADC(3)
  ROWH(0,0,8) ROWH(0,1,9)
  ROWO(0,2,10, ROT0) ROWO(0,3,0, ROT1)
  // ii=3: rc 12-15
  WRITEC(3) __syncthreads(); LOADC(4)
  ROWO(1,0,1, ROT2) ROWO(1,1,2, ROT3) ROWO(1,2,3, ROT4) ROWO(1,3,4, ROT5)
  // ii=4: rc 16-19
  WRITEC(4) __syncthreads(); LOADC(5)
  ROWO(0,0,5, ROT6) ROWO(0,1,6, ROT7) ROWO(0,2,7, ROT8) ROWO(0,3,8, ROT9)
  // ii=5: rc 20-23
  WRITEC(5) __syncthreads(); LOADC(6)
  ROWO(1,0,9, ROT10) ROWO(1,1,10, ROT0) ROWO(1,2,0, ROT1) ROWO(1,3,1, ROT2)
  // ii=6: rc 24-27
  WRITEC(6) __syncthreads(); LOADC(7)
  ROWO(0,0,2, ROT3) ROWO(0,1,3, ROT4) ROWO(0,2,4, ROT5) ROWO(0,3,5, ROT6)
  // ii=7: rc 28-31
  WRITEC(7) __syncthreads(); LOADC(8)
  ROWO(1,0,6, ROT7) ROWO(1,1,7, ROT8) ROWO(1,2,8, ROT9) ROWO(1,3,9, ROT10)
  // ii=8: rc 32-35
  WRITEC(8) __syncthreads(); LOADC(9)
  ROWO(0,0,10, ROT0) ROWO(0,1,0, ROT1) ROWO(0,2,1, ROT2) ROWO(0,3,2, ROT3)
  // ii=9: rc 36-39
  WRITEC(9) __syncthreads(); LOADC(10)
  ROWO(1,0,3, ROT4) ROWO(1,1,4, ROT5) ROWO(1,2,5, ROT6) ROWO(1,3,6, ROT7)
  // ii=10: rc 40,41 (output rows 30,31; rows 42,43 guarded off)
  WRITEC(10) __syncthreads();
  ROWO(0,0,7, ROT8) ROWO(0,1,8, ROT9)

  // Block reduction: wave64 shuffle -> LDS -> one double atomic per block.
#pragma unroll
  for (int off = 32; off > 0; off >>= 1) local += __shfl_down(local, off, 64);
  const int wave = t >> 6;
  const int lane = t & 63;
  if (lane == 0) wsum[wave] = local;
  __syncthreads();
  if (t == 0) {
    float s = 0.f;
#pragma unroll
    for (int w = 0; w < 8; ++w) s += wsum[w];
    atomicAdd(accum, (double)s);
  }
}

__global__ void ssim_final_kernel(const double* __restrict__ accum,
                                  float* __restrict__ out) {
  out[0] = 1.0f - (float)(accum[0] / NPIX);
}

extern "C" void kernel_launch(void* const* d_in, const int* in_sizes, int n_in,
                              void* d_out, int out_size, void* d_ws, size_t ws_size,
                              hipStream_t stream) {
  const float* img1 = (const float*)d_in[0];
  const float* img2 = (const float*)d_in[1];
  double* accum = (double*)d_ws;
  hipMemsetAsync(accum, 0, sizeof(double), stream);

  dim3 grid(HH / TH, BATCH);
  ssim_main_kernel<<<grid, 512, 0, stream>>>(img1, img2, accum);
  ssim_final_kernel<<<1, 1, 0, stream>>>(accum, (float*)d_out);
}